// Round 3
// baseline (876.964 us; speedup 1.0000x reference)
//
#include <hip/hip_runtime.h>
#include <math.h>

#define NTOK 32768
#define HDIM 1024
#define NEXP 64
#define NE   (NTOK * NEXP)
#define CAP  512
#define TB   64
#define CAND 6144
#define QMAX 2048

__device__ __forceinline__ unsigned f2key(float f) {
  unsigned u = __float_as_uint(f);
  return (u & 0x80000000u) ? ~u : (u | 0x80000000u);
}
// Pure key-range coarsening: bin r holds keys with -R in [r, r+1); bin 64 =
// unassigned sentinel. Used consistently in histogram AND extraction, so
// selection is exact regardless of float-rounding at bin edges.
__device__ __forceinline__ int bin_of(unsigned k) {
  if (k & 0x80000000u) return 0;
  float f = __uint_as_float(~k);        // = -R > 0
  f = fminf(f, 64.5f);
  return (int)f;
}

__global__ void init_kernel(unsigned* cnt, float* sumP, unsigned* ghist) {
  int i = blockIdx.x * 256 + threadIdx.x;
  if (i < NEXP) { cnt[i] = 0u; sumP[i] = 0.f; }
  if (i < NEXP * NEXP) ghist[i] = 0u;
}

// R6: lane = token, acc[64] in VGPRs, NO LDS in the GEMM at all.
// - R5 post-mortem: VGPR 84 + WRITE_SIZE 139MB = the compiler spilled the
//   accumulators (live data acc[64]+stg[8]+xr[8] = 128 regs). Fix: drop the
//   prefetch regs AND the x LDS staging entirely.
// - x: each lane reads ITS OWN row. Per 256-k chunk a lane reads one aligned
//   128-B segment (8x float4) = exactly one cache line, fully consumed, read
//   once. No cross-lane x reuse exists in this layout, so staging bought
//   nothing. No __syncthreads in the main loop; waves drift freely.
// - w: wave-uniform address (readfirstlane'd wave id; e,s compile-time; no
//   stores in the loop body, all pointers __restrict) -> scalar s_load path,
//   SGPR-broadcast into v_fmac. w is 256 KB, L2-resident.
// - e-loop FULLY unrolled: partial unroll would runtime-index acc -> scratch.
// - 8 waves split K 8 ways; phase-0-stores/phases-1..7-add LDS reduce.
// Post phase (softmax/rank/hist/transpose) is byte-for-byte the verified code.
// NO min-occupancy arg in launch_bounds (R2/R3 lesson: forced-budget spills).
__global__ __launch_bounds__(512) void router_kernel(
    const float* __restrict__ x, const float* __restrict__ w,
    float* __restrict__ probs, unsigned* __restrict__ keyNE,
    unsigned* __restrict__ keyEN, unsigned long long* __restrict__ assignB,
    unsigned* __restrict__ cnt, float* __restrict__ sumP,
    unsigned* __restrict__ ghist, float* __restrict__ out) {
  __shared__ float    lsf[64 * 65];     // logits   (16640 B)
  __shared__ unsigned kt[64 * 65];      // keys     (16640 B)
  __shared__ unsigned lhist[64 * 65];   // rank histogram (16640 B)

  const int tid  = threadIdx.x;
  const int wid  = tid >> 6, lane = tid & 63;
  const int uw   = __builtin_amdgcn_readfirstlane(wid);  // provably uniform
  const int t0   = blockIdx.x * TB;

  float acc[64];
#pragma unroll
  for (int e = 0; e < 64; ++e) acc[e] = 0.f;

  // lane's own token row; wave uw owns k-columns [uw*32 + c*256, +32)
  const float* xp  = x + (size_t)(t0 + lane) * HDIM + uw * 32;
  const float* wp0 = w + uw * 32;

#pragma unroll 1
  for (int c = 0; c < HDIM / 256; ++c) {
    const int c0 = c * 256;
    float4 xr[8];
#pragma unroll
    for (int s = 0; s < 8; ++s)
      xr[s] = *(const float4*)(xp + c0 + s * 4);
#pragma unroll
    for (int e = 0; e < 64; ++e) {
      const float* wp = wp0 + (size_t)e * HDIM + c0;
#pragma unroll
      for (int s = 0; s < 8; ++s) {
        float4 wv = *(const float4*)(wp + s * 4);
        acc[e] = fmaf(xr[s].x, wv.x, acc[e]);
        acc[e] = fmaf(xr[s].y, wv.y, acc[e]);
        acc[e] = fmaf(xr[s].z, wv.z, acc[e]);
        acc[e] = fmaf(xr[s].w, wv.w, acc[e]);
      }
    }
  }

  // ---- zero rank histogram (lsf is fully written by phase 0 below)
  for (int i = tid; i < 64 * 65; i += 512) lhist[i] = 0u;
  __syncthreads();
  // ---- deterministic 8-phase cross-wave K-reduce (lane = token row).
  // Phase 0 stores, phases 1..7 accumulate. Static acc indices throughout.
  if (wid == 0) {
#pragma unroll
    for (int e = 0; e < 64; ++e) lsf[lane * 65 + e] = acc[e];
  }
  __syncthreads();
#pragma unroll 1
  for (int ph = 1; ph < 8; ++ph) {
    if (wid == ph) {
#pragma unroll
      for (int e = 0; e < 64; ++e) lsf[lane * 65 + e] += acc[e];
    }
    __syncthreads();
  }

  // ---- post phase: unchanged verified code (lane = expert) ----
  for (int i = 0; i < 8; ++i) {
    const int tl = wid * 8 + i;
    const int t  = t0 + tl;
    float l = lsf[tl * 65 + lane];
    float mx = l;
#pragma unroll
    for (int m = 32; m >= 1; m >>= 1) mx = fmaxf(mx, __shfl_xor(mx, m));
    float ex = expf(l - mx);
    float ssum = ex;
#pragma unroll
    for (int m = 32; m >= 1; m >>= 1) ssum += __shfl_xor(ssum, m);
    float p = ex / ssum;
    int rank = 0; float csum = p;
#pragma unroll
    for (int d = 1; d < 64; ++d) {
      float pj = __shfl_xor(p, d);
      int H = d; H |= H >> 1; H |= H >> 2; H |= H >> 4; H -= (H >> 1);
      bool jlt = (lane & H) != 0;                 // j = lane^d < lane
      bool gt = (pj > p) || (pj == p && jlt);
      rank += gt ? 1 : 0;
      csum += gt ? pj : 0.f;
    }
    int kc = (csum >= 0.9f) ? rank : 63;
#pragma unroll
    for (int m = 32; m >= 1; m >>= 1) kc = min(kc, __shfl_xor(kc, m));
    const bool assign = (rank <= kc);
    float R = assign ? (p - (float)(rank + 1)) : -1e9f;
    unsigned key = f2key(R);
    probs[(size_t)t * NEXP + lane] = p;
    keyNE[(size_t)t * NEXP + lane] = key;
    kt[tl * 65 + lane] = key;
    // 64 lanes -> 64 distinct expert rows: zero same-address LDS conflicts
    atomicAdd(&lhist[lane * 65 + bin_of(key)], 1u);
    unsigned long long ab = __ballot(assign);
    if (lane == 0) assignB[t] = ab;
    if (rank == 0) {
      out[(size_t)2 * NE + 1 + t] = (float)lane;
      atomicAdd(&cnt[lane], 1u);
      atomicAdd(&sumP[lane], p);
    }
  }
  __syncthreads();
#pragma unroll
  for (int r = 0; r < 8; ++r) {
    int idx = tid + r * 512;
    int e = idx >> 6, tl = idx & 63;
    keyEN[(size_t)e * NTOK + t0 + tl] = kt[tl * 65 + e];
  }
  for (int idx = tid; idx < NEXP * NEXP; idx += 512) {   // merge nonzero bins
    int ee = idx >> 6, b = idx & 63;
    unsigned v = lhist[ee * 65 + b];
    if (v) atomicAdd(&ghist[idx], v);
  }
}

// One block per expert. Boundary bin comes precomputed from ghist; one
// extraction scan + exact (key desc, token asc) quadratic tie-cut, with
// byte-narrowing backstops for pathological bin populations.
__global__ __launch_bounds__(1024) void select_kernel(
    const unsigned* __restrict__ keyEN, const unsigned* __restrict__ ghist,
    unsigned* __restrict__ theta, int* __restrict__ tieCut) {
  const int e = blockIdx.x;
  const unsigned* col = keyEN + (size_t)e * NTOK;
  const int tid = threadIdx.x, wid = tid >> 6;
  __shared__ unsigned wh[16][256];
  __shared__ unsigned h[256];
  __shared__ unsigned cA_k[CAND], cA_t[CAND], cB_k[CAND], cB_t[CAND];
  __shared__ unsigned s_n, s_b;
  __shared__ int s_rb, s_need, s_cnt;
  __shared__ unsigned s_theta; __shared__ int s_cut;

  if (tid == 0) {
    unsigned run = 0; int rb = -1, need = 0, cc = 0;
    for (int r = 0; r < 64; ++r) {
      unsigned c = ghist[e * 64 + r];
      if (rb < 0 && run + c >= CAP) { rb = r; need = CAP - (int)run; cc = (int)c; }
      run += c;
    }
    s_rb = rb; s_need = need; s_cnt = cc;
  }
  __syncthreads();
  if (s_rb < 0) {   // fewer than CAP assigned: keep all assigned
    if (tid == 0) { theta[e] = f2key(-1e9f); tieCut[e] = -1; }
    return;
  }
  const int rb = s_rb;
  int need = s_need, cnt = s_cnt;
  unsigned pmask = 0u, pval = 0u;
  int level = 0;

  while (cnt > CAND && level < 4) {   // global byte-narrowing (backstop)
    const int sh = 24 - 8 * level;
    for (int r = tid; r < 16 * 256; r += 1024) ((unsigned*)wh)[r] = 0u;
    __syncthreads();
    for (int t = tid; t < NTOK; t += 1024) {
      unsigned k = col[t];
      if (bin_of(k) == rb && (k & pmask) == pval)
        atomicAdd(&wh[wid][(k >> sh) & 255u], 1u);
    }
    __syncthreads();
    if (tid < 256) {
      unsigned s = 0;
      for (int wv = 0; wv < 16; ++wv) s += wh[wv][tid];
      h[tid] = s;
    }
    __syncthreads();
    if (tid == 0) {
      unsigned cum = 0;
      for (int d = 255; d >= 0; --d) {
        if (cum + h[d] >= (unsigned)need) {
          s_b = (unsigned)d; s_need = need - (int)cum; s_cnt = (int)h[d];
          break;
        }
        cum += h[d];
      }
    }
    __syncthreads();
    need = s_need; cnt = s_cnt;
    pmask |= (255u << sh); pval |= (s_b << sh);
    level++;
    __syncthreads();
  }

  if (cnt > CAND) {   // key fully determined == pval; tie purely on token idx
    int lo = 0, hi = NTOK - 1;
    while (lo < hi) {
      int mid = (lo + hi) >> 1;
      if (tid == 0) s_n = 0u;
      __syncthreads();
      for (int t = tid; t <= mid; t += 1024)
        if (col[t] == pval) atomicAdd(&s_n, 1u);
      __syncthreads();
      if ((int)s_n >= need) hi = mid; else lo = mid + 1;
      __syncthreads();
    }
    if (tid == 0) { theta[e] = pval; tieCut[e] = lo; }
    return;
  }

  if (tid == 0) s_n = 0u;
  __syncthreads();
  for (int t = tid; t < NTOK; t += 1024) {   // extraction scan
    unsigned k = col[t];
    if (bin_of(k) == rb && (k & pmask) == pval) {
      unsigned i = atomicAdd(&s_n, 1u);
      cA_k[i] = k; cA_t[i] = (unsigned)t;
    }
  }
  __syncthreads();
  unsigned* ck = cA_k; unsigned* ct = cA_t;
  unsigned* nk = cB_k; unsigned* nt2 = cB_t;

  while (cnt > QMAX && level < 4) {   // in-LDS byte-narrowing
    const int sh = 24 - 8 * level;
    for (int r = tid; r < 16 * 256; r += 1024) ((unsigned*)wh)[r] = 0u;
    __syncthreads();
    for (int i = tid; i < cnt; i += 1024)
      atomicAdd(&wh[wid][(ck[i] >> sh) & 255u], 1u);
    __syncthreads();
    if (tid < 256) {
      unsigned s = 0;
      for (int wv = 0; wv < 16; ++wv) s += wh[wv][tid];
      h[tid] = s;
    }
    __syncthreads();
    if (tid == 0) {
      unsigned cum = 0;
      for (int d = 255; d >= 0; --d) {
        if (cum + h[d] >= (unsigned)need) {
          s_b = (unsigned)d; s_need = need - (int)cum; s_cnt = (int)h[d];
          break;
        }
        cum += h[d];
      }
      s_n = 0u;
    }
    __syncthreads();
    for (int i = tid; i < cnt; i += 1024) {
      if (((ck[i] >> sh) & 255u) == s_b) {
        unsigned j = atomicAdd(&s_n, 1u);
        nk[j] = ck[i]; nt2[j] = ct[i];
      }
    }
    __syncthreads();
    { unsigned* t1 = ck; ck = nk; nk = t1; t1 = ct; ct = nt2; nt2 = t1; }
    need = s_need; cnt = s_cnt; level++;
    __syncthreads();
  }

  for (int i = tid; i < cnt; i += 1024) {   // exact: need-th in strict order
    unsigned ki = ck[i], ti = ct[i];
    int c = 0;
    for (int j = 0; j < cnt; ++j) {
      unsigned kj = ck[j], tj = ct[j];
      c += (kj > ki || (kj == ki && tj < ti)) ? 1 : 0;
    }
    if (c == need - 1) { s_theta = ki; s_cut = (int)ti; }
  }
  __syncthreads();
  if (tid == 0) { theta[e] = s_theta; tieCut[e] = s_cut; }
}

__global__ __launch_bounds__(256) void write_kernel(
    const float* __restrict__ probs, const unsigned* __restrict__ keyNE,
    const unsigned long long* __restrict__ assignB,
    const unsigned* __restrict__ theta, const int* __restrict__ tieCut,
    const unsigned* __restrict__ cnt, const float* __restrict__ sumP,
    float* __restrict__ out) {
  const int id = blockIdx.x * 256 + threadIdx.x;
  const int t = id >> 6, e = id & 63;
  unsigned k = keyNE[id];
  float p = probs[id];
  bool a = (assignB[t] >> e) & 1ull;
  unsigned th = theta[e];
  int cut = tieCut[e];
  bool keep = (k > th) || ((k == th) && (t <= cut));
  bool msk = a && keep;
  out[id] = msk ? 1.f : 0.f;
  out[(size_t)NE + id] = msk ? p : 0.f;
  if (blockIdx.x == 0 && threadIdx.x < 64) {
    int ee = threadIdx.x;
    float v = ((float)cnt[ee] / (float)NTOK) * (sumP[ee] / (float)NTOK);
#pragma unroll
    for (int m = 32; m >= 1; m >>= 1) v += __shfl_xor(v, m);
    if (ee == 0) out[(size_t)2 * NE] = (float)NEXP * v * 0.01f;
  }
}

extern "C" void kernel_launch(void* const* d_in, const int* in_sizes, int n_in,
                              void* d_out, int out_size, void* d_ws, size_t ws_size,
                              hipStream_t stream) {
  const float* x = (const float*)d_in[0];
  const float* w = (const float*)d_in[1];
  float* out = (float*)d_out;

  char* ws = (char*)d_ws;
  float* probs                 = (float*)ws;
  unsigned* keyNE              = (unsigned*)(probs + NE);
  unsigned* keyEN              = keyNE + NE;
  unsigned long long* assignB  = (unsigned long long*)(keyEN + NE);
  unsigned* cnt                = (unsigned*)(assignB + NTOK);
  float* sumP                  = (float*)(cnt + NEXP);
  unsigned* theta              = (unsigned*)(sumP + NEXP);
  int* tieCut                  = (int*)(theta + NEXP);
  unsigned* ghist              = (unsigned*)(tieCut + NEXP);

  init_kernel<<<16, 256, 0, stream>>>(cnt, sumP, ghist);
  router_kernel<<<NTOK / TB, 512, 0, stream>>>(x, w, probs, keyNE, keyEN,
                                               assignB, cnt, sumP, ghist, out);
  select_kernel<<<NEXP, 1024, 0, stream>>>(keyEN, ghist, theta, tieCut);
  write_kernel<<<NE / 256, 256, 0, stream>>>(probs, keyNE, assignB, theta,
                                             tieCut, cnt, sumP, out);
}

// Round 4
// 684.329 us; speedup vs baseline: 1.2815x; 1.2815x over previous
//
#include <hip/hip_runtime.h>
#include <math.h>

#define NTOK 32768
#define HDIM 1024
#define NEXP 64
#define NE   (NTOK * NEXP)
#define CAP  512
#define TB   64
#define CAND 6144
#define QMAX 2048

__device__ __forceinline__ unsigned f2key(float f) {
  unsigned u = __float_as_uint(f);
  return (u & 0x80000000u) ? ~u : (u | 0x80000000u);
}
// Pure key-range coarsening: bin r holds keys with -R in [r, r+1); bin 64 =
// unassigned sentinel. Used consistently in histogram AND extraction, so
// selection is exact regardless of float-rounding at bin edges.
__device__ __forceinline__ int bin_of(unsigned k) {
  if (k & 0x80000000u) return 0;
  float f = __uint_as_float(~k);        // = -R > 0
  f = fminf(f, 64.5f);
  return (int)f;
}

__global__ void init_kernel(unsigned* cnt, float* sumP, unsigned* ghist) {
  int i = blockIdx.x * 256 + threadIdx.x;
  if (i < NEXP) { cnt[i] = 0u; sumP[i] = 0.f; }
  if (i < NEXP * NEXP) ghist[i] = 0u;
}

// R7: lane = token, GEMM with NO LDS and NO spill.
// - R5/R6 post-mortem: allocator pins this kernel at ~85 VGPR (6 waves/SIMD
//   target given 50KB LDS -> 3 blocks/CU); acc[64] (R6 demand ~110+) spilled
//   ~25 regs/lane -> WRITE_SIZE 80MB, FETCH 166MB, VALUBusy 22%. Fix: fit
//   UNDER the cap instead of fighting it.
// - 8 waves = 4 expert-groups x 2 K-halves. Wave owns experts [eg*16,+16),
//   K [kh*512,+512). Working set: acc[16] + xr[8](32) + wv/addr ~= 70 VGPR.
//   FMAs/lane unchanged (16e x 512k = 8192).
// - x: each lane reads ITS OWN row (one 128B segment / 32-float chunk, each
//   line read exactly once). No x staging: no cross-lane x reuse exists.
// - w: fully wave-uniform addresses (readfirstlane'd wid; e,s,c compile-time
//   or uniform) -> scalar s_load path, SGPR-broadcast into v_fmac. 256 KB,
//   L2-resident.
// - e/s loops FULLY unrolled (static acc index; runtime index -> scratch).
// - Reduce: expert-groups write disjoint lsf columns -> only 2 phases
//   (kh=0 waves store, kh=1 waves add).
// Post phase (softmax/rank/hist/transpose) is byte-for-byte the verified code.
// NO min-occupancy arg in launch_bounds (R2/R3 lesson: forced-budget spills).
__global__ __launch_bounds__(512) void router_kernel(
    const float* __restrict__ x, const float* __restrict__ w,
    float* __restrict__ probs, unsigned* __restrict__ keyNE,
    unsigned* __restrict__ keyEN, unsigned long long* __restrict__ assignB,
    unsigned* __restrict__ cnt, float* __restrict__ sumP,
    unsigned* __restrict__ ghist, float* __restrict__ out) {
  __shared__ float    lsf[64 * 65];     // logits   (16640 B)
  __shared__ unsigned kt[64 * 65];      // keys     (16640 B)
  __shared__ unsigned lhist[64 * 65];   // rank histogram (16640 B)

  const int tid  = threadIdx.x;
  const int wid  = tid >> 6, lane = tid & 63;
  const int uw   = __builtin_amdgcn_readfirstlane(wid);  // provably uniform
  const int ueg  = uw >> 1;             // expert group: 16 experts
  const int ukh  = uw & 1;              // K half: 512 floats
  const int t0   = blockIdx.x * TB;

  float acc[16];
#pragma unroll
  for (int e = 0; e < 16; ++e) acc[e] = 0.f;

  // lane's own token row, wave's K-half; w base for wave's expert group
  const float* xp  = x + (size_t)(t0 + lane) * HDIM + ukh * 512;
  const float* wp0 = w + (size_t)ueg * 16 * HDIM + ukh * 512;

#pragma unroll 1
  for (int c = 0; c < 16; ++c) {        // 16 chunks x 32 floats = 512 K
    const int c0 = c * 32;
    float4 xr[8];
#pragma unroll
    for (int s = 0; s < 8; ++s)
      xr[s] = *(const float4*)(xp + c0 + s * 4);
#pragma unroll
    for (int e = 0; e < 16; ++e) {
      const float* wp = wp0 + (size_t)e * HDIM + c0;
#pragma unroll
      for (int s = 0; s < 8; ++s) {
        float4 wv = *(const float4*)(wp + s * 4);
        acc[e] = fmaf(xr[s].x, wv.x, acc[e]);
        acc[e] = fmaf(xr[s].y, wv.y, acc[e]);
        acc[e] = fmaf(xr[s].z, wv.z, acc[e]);
        acc[e] = fmaf(xr[s].w, wv.w, acc[e]);
      }
    }
  }

  // ---- zero rank histogram; 2-phase cross-wave K-reduce (lane = token row,
  //      expert groups hit disjoint columns -> no race within a phase)
  for (int i = tid; i < 64 * 65; i += 512) lhist[i] = 0u;
  if ((wid & 1) == 0) {                 // kh=0 waves store
#pragma unroll
    for (int e = 0; e < 16; ++e) lsf[lane * 65 + ueg * 16 + e] = acc[e];
  }
  __syncthreads();
  if ((wid & 1) == 1) {                 // kh=1 waves accumulate
#pragma unroll
    for (int e = 0; e < 16; ++e) lsf[lane * 65 + ueg * 16 + e] += acc[e];
  }
  __syncthreads();

  // ---- post phase: unchanged verified code (lane = expert) ----
  for (int i = 0; i < 8; ++i) {
    const int tl = wid * 8 + i;
    const int t  = t0 + tl;
    float l = lsf[tl * 65 + lane];
    float mx = l;
#pragma unroll
    for (int m = 32; m >= 1; m >>= 1) mx = fmaxf(mx, __shfl_xor(mx, m));
    float ex = expf(l - mx);
    float ssum = ex;
#pragma unroll
    for (int m = 32; m >= 1; m >>= 1) ssum += __shfl_xor(ssum, m);
    float p = ex / ssum;
    int rank = 0; float csum = p;
#pragma unroll
    for (int d = 1; d < 64; ++d) {
      float pj = __shfl_xor(p, d);
      int H = d; H |= H >> 1; H |= H >> 2; H |= H >> 4; H -= (H >> 1);
      bool jlt = (lane & H) != 0;                 // j = lane^d < lane
      bool gt = (pj > p) || (pj == p && jlt);
      rank += gt ? 1 : 0;
      csum += gt ? pj : 0.f;
    }
    int kc = (csum >= 0.9f) ? rank : 63;
#pragma unroll
    for (int m = 32; m >= 1; m >>= 1) kc = min(kc, __shfl_xor(kc, m));
    const bool assign = (rank <= kc);
    float R = assign ? (p - (float)(rank + 1)) : -1e9f;
    unsigned key = f2key(R);
    probs[(size_t)t * NEXP + lane] = p;
    keyNE[(size_t)t * NEXP + lane] = key;
    kt[tl * 65 + lane] = key;
    // 64 lanes -> 64 distinct expert rows: zero same-address LDS conflicts
    atomicAdd(&lhist[lane * 65 + bin_of(key)], 1u);
    unsigned long long ab = __ballot(assign);
    if (lane == 0) assignB[t] = ab;
    if (rank == 0) {
      out[(size_t)2 * NE + 1 + t] = (float)lane;
      atomicAdd(&cnt[lane], 1u);
      atomicAdd(&sumP[lane], p);
    }
  }
  __syncthreads();
#pragma unroll
  for (int r = 0; r < 8; ++r) {
    int idx = tid + r * 512;
    int e = idx >> 6, tl = idx & 63;
    keyEN[(size_t)e * NTOK + t0 + tl] = kt[tl * 65 + e];
  }
  for (int idx = tid; idx < NEXP * NEXP; idx += 512) {   // merge nonzero bins
    int ee = idx >> 6, b = idx & 63;
    unsigned v = lhist[ee * 65 + b];
    if (v) atomicAdd(&ghist[idx], v);
  }
}

// One block per expert. Boundary bin comes precomputed from ghist; one
// extraction scan + exact (key desc, token asc) quadratic tie-cut, with
// byte-narrowing backstops for pathological bin populations.
__global__ __launch_bounds__(1024) void select_kernel(
    const unsigned* __restrict__ keyEN, const unsigned* __restrict__ ghist,
    unsigned* __restrict__ theta, int* __restrict__ tieCut) {
  const int e = blockIdx.x;
  const unsigned* col = keyEN + (size_t)e * NTOK;
  const int tid = threadIdx.x, wid = tid >> 6;
  __shared__ unsigned wh[16][256];
  __shared__ unsigned h[256];
  __shared__ unsigned cA_k[CAND], cA_t[CAND], cB_k[CAND], cB_t[CAND];
  __shared__ unsigned s_n, s_b;
  __shared__ int s_rb, s_need, s_cnt;
  __shared__ unsigned s_theta; __shared__ int s_cut;

  if (tid == 0) {
    unsigned run = 0; int rb = -1, need = 0, cc = 0;
    for (int r = 0; r < 64; ++r) {
      unsigned c = ghist[e * 64 + r];
      if (rb < 0 && run + c >= CAP) { rb = r; need = CAP - (int)run; cc = (int)c; }
      run += c;
    }
    s_rb = rb; s_need = need; s_cnt = cc;
  }
  __syncthreads();
  if (s_rb < 0) {   // fewer than CAP assigned: keep all assigned
    if (tid == 0) { theta[e] = f2key(-1e9f); tieCut[e] = -1; }
    return;
  }
  const int rb = s_rb;
  int need = s_need, cnt = s_cnt;
  unsigned pmask = 0u, pval = 0u;
  int level = 0;

  while (cnt > CAND && level < 4) {   // global byte-narrowing (backstop)
    const int sh = 24 - 8 * level;
    for (int r = tid; r < 16 * 256; r += 1024) ((unsigned*)wh)[r] = 0u;
    __syncthreads();
    for (int t = tid; t < NTOK; t += 1024) {
      unsigned k = col[t];
      if (bin_of(k) == rb && (k & pmask) == pval)
        atomicAdd(&wh[wid][(k >> sh) & 255u], 1u);
    }
    __syncthreads();
    if (tid < 256) {
      unsigned s = 0;
      for (int wv = 0; wv < 16; ++wv) s += wh[wv][tid];
      h[tid] = s;
    }
    __syncthreads();
    if (tid == 0) {
      unsigned cum = 0;
      for (int d = 255; d >= 0; --d) {
        if (cum + h[d] >= (unsigned)need) {
          s_b = (unsigned)d; s_need = need - (int)cum; s_cnt = (int)h[d];
          break;
        }
        cum += h[d];
      }
    }
    __syncthreads();
    need = s_need; cnt = s_cnt;
    pmask |= (255u << sh); pval |= (s_b << sh);
    level++;
    __syncthreads();
  }

  if (cnt > CAND) {   // key fully determined == pval; tie purely on token idx
    int lo = 0, hi = NTOK - 1;
    while (lo < hi) {
      int mid = (lo + hi) >> 1;
      if (tid == 0) s_n = 0u;
      __syncthreads();
      for (int t = tid; t <= mid; t += 1024)
        if (col[t] == pval) atomicAdd(&s_n, 1u);
      __syncthreads();
      if ((int)s_n >= need) hi = mid; else lo = mid + 1;
      __syncthreads();
    }
    if (tid == 0) { theta[e] = pval; tieCut[e] = lo; }
    return;
  }

  if (tid == 0) s_n = 0u;
  __syncthreads();
  for (int t = tid; t < NTOK; t += 1024) {   // extraction scan
    unsigned k = col[t];
    if (bin_of(k) == rb && (k & pmask) == pval) {
      unsigned i = atomicAdd(&s_n, 1u);
      cA_k[i] = k; cA_t[i] = (unsigned)t;
    }
  }
  __syncthreads();
  unsigned* ck = cA_k; unsigned* ct = cA_t;
  unsigned* nk = cB_k; unsigned* nt2 = cB_t;

  while (cnt > QMAX && level < 4) {   // in-LDS byte-narrowing
    const int sh = 24 - 8 * level;
    for (int r = tid; r < 16 * 256; r += 1024) ((unsigned*)wh)[r] = 0u;
    __syncthreads();
    for (int i = tid; i < cnt; i += 1024)
      atomicAdd(&wh[wid][(ck[i] >> sh) & 255u], 1u);
    __syncthreads();
    if (tid < 256) {
      unsigned s = 0;
      for (int wv = 0; wv < 16; ++wv) s += wh[wv][tid];
      h[tid] = s;
    }
    __syncthreads();
    if (tid == 0) {
      unsigned cum = 0;
      for (int d = 255; d >= 0; --d) {
        if (cum + h[d] >= (unsigned)need) {
          s_b = (unsigned)d; s_need = need - (int)cum; s_cnt = (int)h[d];
          break;
        }
        cum += h[d];
      }
      s_n = 0u;
    }
    __syncthreads();
    for (int i = tid; i < cnt; i += 1024) {
      if (((ck[i] >> sh) & 255u) == s_b) {
        unsigned j = atomicAdd(&s_n, 1u);
        nk[j] = ck[i]; nt2[j] = ct[i];
      }
    }
    __syncthreads();
    { unsigned* t1 = ck; ck = nk; nk = t1; t1 = ct; ct = nt2; nt2 = t1; }
    need = s_need; cnt = s_cnt; level++;
    __syncthreads();
  }

  for (int i = tid; i < cnt; i += 1024) {   // exact: need-th in strict order
    unsigned ki = ck[i], ti = ct[i];
    int c = 0;
    for (int j = 0; j < cnt; ++j) {
      unsigned kj = ck[j], tj = ct[j];
      c += (kj > ki || (kj == ki && tj < ti)) ? 1 : 0;
    }
    if (c == need - 1) { s_theta = ki; s_cut = (int)ti; }
  }
  __syncthreads();
  if (tid == 0) { theta[e] = s_theta; tieCut[e] = s_cut; }
}

__global__ __launch_bounds__(256) void write_kernel(
    const float* __restrict__ probs, const unsigned* __restrict__ keyNE,
    const unsigned long long* __restrict__ assignB,
    const unsigned* __restrict__ theta, const int* __restrict__ tieCut,
    const unsigned* __restrict__ cnt, const float* __restrict__ sumP,
    float* __restrict__ out) {
  const int id = blockIdx.x * 256 + threadIdx.x;
  const int t = id >> 6, e = id & 63;
  unsigned k = keyNE[id];
  float p = probs[id];
  bool a = (assignB[t] >> e) & 1ull;
  unsigned th = theta[e];
  int cut = tieCut[e];
  bool keep = (k > th) || ((k == th) && (t <= cut));
  bool msk = a && keep;
  out[id] = msk ? 1.f : 0.f;
  out[(size_t)NE + id] = msk ? p : 0.f;
  if (blockIdx.x == 0 && threadIdx.x < 64) {
    int ee = threadIdx.x;
    float v = ((float)cnt[ee] / (float)NTOK) * (sumP[ee] / (float)NTOK);
#pragma unroll
    for (int m = 32; m >= 1; m >>= 1) v += __shfl_xor(v, m);
    if (ee == 0) out[(size_t)2 * NE] = (float)NEXP * v * 0.01f;
  }
}

extern "C" void kernel_launch(void* const* d_in, const int* in_sizes, int n_in,
                              void* d_out, int out_size, void* d_ws, size_t ws_size,
                              hipStream_t stream) {
  const float* x = (const float*)d_in[0];
  const float* w = (const float*)d_in[1];
  float* out = (float*)d_out;

  char* ws = (char*)d_ws;
  float* probs                 = (float*)ws;
  unsigned* keyNE              = (unsigned*)(probs + NE);
  unsigned* keyEN              = keyNE + NE;
  unsigned long long* assignB  = (unsigned long long*)(keyEN + NE);
  unsigned* cnt                = (unsigned*)(assignB + NTOK);
  float* sumP                  = (float*)(cnt + NEXP);
  unsigned* theta              = (unsigned*)(sumP + NEXP);
  int* tieCut                  = (int*)(theta + NEXP);
  unsigned* ghist              = (unsigned*)(tieCut + NEXP);

  init_kernel<<<16, 256, 0, stream>>>(cnt, sumP, ghist);
  router_kernel<<<NTOK / TB, 512, 0, stream>>>(x, w, probs, keyNE, keyEN,
                                               assignB, cnt, sumP, ghist, out);
  select_kernel<<<NEXP, 1024, 0, stream>>>(keyEN, ghist, theta, tieCut);
  write_kernel<<<NE / 256, 256, 0, stream>>>(probs, keyNE, assignB, theta,
                                             tieCut, cnt, sumP, out);
}